// Round 14
// baseline (1328.535 us; speedup 1.0000x reference)
//
#include <hip/hip_runtime.h>
#include <math.h>

#define THREADS 1024
#define WPB 16       // 16 waves per block
#define EPW 2        // 2 batch elements per wave -> each WtL ds_read feeds 8 FMAs

// ---- 16-lane-row sum via DPP row rotates (VALU pipe, no LDS) ----
template<int CTRL>
__device__ __forceinline__ float dpp_add(float x) {
    int xi = __builtin_bit_cast(int, x);
    int yi = __builtin_amdgcn_update_dpp(0, xi, CTRL, 0xF, 0xF, false);
    return x + __builtin_bit_cast(float, yi);
}
__device__ __forceinline__ float row16_sum(float x) {
    x = dpp_add<0x121>(x);  // row_ror:1
    x = dpp_add<0x122>(x);  // row_ror:2
    x = dpp_add<0x124>(x);  // row_ror:4
    x = dpp_add<0x128>(x);  // row_ror:8
    return x;               // every lane in its 16-row holds the row sum
}
// ---- k-reduction across the 4 kq lanes: lane^16 (swizzle) + lane^32 (shfl) ----
__device__ __forceinline__ float kq_sum(float x) {
    int y = __builtin_amdgcn_ds_swizzle(__builtin_bit_cast(int, x), 0x401F); // ^16
    x += __builtin_bit_cast(float, y);
    x += __shfl_xor(x, 32, 64);                                             // ^32
    return x;
}
__device__ __forceinline__ float rcpf_(float x) { return __builtin_amdgcn_rcpf(x); }

// One 1024-thread block = 16 waves = 32 batch elements (2 per wave).
// WtL (transposed W, 56 KB) staged once per block; EPW=2 halves the DS-pipe
// cost per element of the u_hat phase (the R13-measured bottleneck).
// x is read directly from global (L1-broadcast) - no xs in LDS.
// Per-wave lane layout: l = (kq = l>>4 k-quarter, t = l&15 capsule m).
__global__ __launch_bounds__(THREADS) void capsnet_kernel(
    const float* __restrict__ x,      // [B,210]
    const float* __restrict__ W_pc,   // [7,8,30]
    const float* __restrict__ b_pc,   // [7,8]
    const float* __restrict__ W,      // [7,12,8,16]
    const int*  __restrict__ p_niter,
    float* __restrict__ out,          // [B,12]
    int B)
{
    __shared__ float4 WtL[3584];            // Wt[(n*8+j)*64 + l], 56 KB
    __shared__ float  us[WPB * EPW][56];    // primary capsules, 7 KB

    const int tid = threadIdx.x;
    const int w   = tid >> 6;      // wave within block (0..15)
    const int l   = tid & 63;      // lane within wave
    const int kq  = l >> 4;        // k-quarter: owns k = kq*4 .. kq*4+3
    const int t   = l & 15;        // candidate capsule index
    int b0 = (blockIdx.x * WPB + w) * EPW;
    if (b0 + EPW > B) b0 = B - EPW;   // clamp; duplicates write identical values
    const int niter = *p_niter;

    // ---- stage Wt into LDS (transpose folded in; 3584 float4 over 1024 thr) ----
    #pragma unroll
    for (int rep = 0; rep < 4; ++rep) {
        int i = tid + THREADS * rep;
        if (i < 3584) {
            int lL  = i & 63;
            int r   = i >> 6;          // n*8 + j
            int j   = r & 7;
            int n   = r >> 3;
            int kqL = lL >> 4;
            int tL  = lL & 15;
            int mm  = (tL < 12) ? tL : 11;
            WtL[i] = *(const float4*)(W + (((size_t)(n * 12 + mm) * 8 + j) * 16 + kqL * 4));
        }
    }

    // ---- primary capsules straight from global x (L1 broadcast across the
    //      8 lanes sharing each n); no xs staging -> DS pipe freed ----
    #pragma unroll
    for (int e = 0; e < EPW; ++e) {
        if (l < 56) {
            int n = l >> 3;
            const float2* wrow2 = (const float2*)(W_pc + l * 30);
            const float2* xr2   = (const float2*)(x + (size_t)(b0 + e) * 210 + n * 30);
            float acc = b_pc[l];
            #pragma unroll
            for (int gg = 0; gg < 15; ++gg) {
                float2 wv = wrow2[gg];
                float2 xv = xr2[gg];
                acc += xv.x * wv.x;
                acc += xv.y * wv.y;
            }
            us[w * EPW + e][l] = acc;
        }
    }
    __syncthreads();   // covers WtL staging + us writes

    // ---- squash primary capsules: 14 lanes per wave (2 elems x 7 n) ----
    if (l < 14) {
        int se = (l >= 7);
        int sn = l - (se ? 7 : 0);
        float vals[8];
        float s2 = 0.f;
        #pragma unroll
        for (int o = 0; o < 8; ++o) {
            vals[o] = us[w * EPW + se][sn * 8 + o];
            s2 += vals[o] * vals[o];
        }
        float nrm = sqrtf(s2);
        float f = nrm * rcpf_((1.f + s2) * (nrm + 1e-8f));
        #pragma unroll
        for (int o = 0; o < 8; ++o) us[w * EPW + se][sn * 8 + o] = vals[o] * f;
    }
    __syncthreads();

    // ---- u_hat[e][n][kk]: each WtL ds_read_b128 feeds 2 elements (8 FMAs) ----
    float uh[EPW][7][4];
    #pragma unroll
    for (int n = 0; n < 7; ++n) {
        float uu[EPW][8];
        #pragma unroll
        for (int e = 0; e < EPW; ++e) {
            float4 a  = *(const float4*)&us[w * EPW + e][n * 8];
            float4 c4 = *(const float4*)&us[w * EPW + e][n * 8 + 4];
            uu[e][0] = a.x;  uu[e][1] = a.y;  uu[e][2] = a.z;  uu[e][3] = a.w;
            uu[e][4] = c4.x; uu[e][5] = c4.y; uu[e][6] = c4.z; uu[e][7] = c4.w;
        }
        #pragma unroll
        for (int e = 0; e < EPW; ++e)
            #pragma unroll
            for (int kk = 0; kk < 4; ++kk) uh[e][n][kk] = 0.f;
        #pragma unroll
        for (int j = 0; j < 8; ++j) {
            float4 wv = WtL[(n * 8 + j) * 64 + l];   // ds_read_b128
            #pragma unroll
            for (int e = 0; e < EPW; ++e) {
                float uj = uu[e][j];
                uh[e][n][0] += uj * wv.x;  uh[e][n][1] += uj * wv.y;
                uh[e][n][2] += uj * wv.z;  uh[e][n][3] += uj * wv.w;
            }
        }
    }

    // ---- dynamic routing: element-sequential (caps live registers) ----
    const bool active = (t < 12);
    float blog[EPW][7];
    float vnorm[EPW];
    #pragma unroll
    for (int e = 0; e < EPW; ++e) vnorm[e] = 0.f;

    // iteration 0: b == 0 => c == 1/12 exactly (softmax of zeros)
    #pragma unroll
    for (int e = 0; e < EPW; ++e) {
        float s[4];
        #pragma unroll
        for (int kk = 0; kk < 4; ++kk) s[kk] = uh[e][0][kk];
        #pragma unroll
        for (int n = 1; n < 7; ++n)
            #pragma unroll
            for (int kk = 0; kk < 4; ++kk) s[kk] += uh[e][n][kk];
        const float c0 = 1.0f / 12.0f;
        #pragma unroll
        for (int kk = 0; kk < 4; ++kk) s[kk] *= c0;
        float s2l = 0.f;
        #pragma unroll
        for (int kk = 0; kk < 4; ++kk) s2l += s[kk] * s[kk];
        float s2 = kq_sum(s2l);            // full 16-k norm^2
        float nrm = sqrtf(s2);
        float f = nrm * rcpf_((1.f + s2) * (nrm + 1e-8f));
        if (niter == 1) {
            vnorm[e] = f * nrm;
        } else {
            #pragma unroll
            for (int kk = 0; kk < 4; ++kk) s[kk] *= f;   // s -> v (my k-quarter)
            #pragma unroll
            for (int n = 0; n < 7; ++n) {
                float dl = 0.f;
                #pragma unroll
                for (int kk = 0; kk < 4; ++kk) dl += uh[e][n][kk] * s[kk];
                blog[e][n] = kq_sum(dl);    // full dot over 16 k
            }
        }
    }

    for (int it = 1; it < niter; ++it) {
        #pragma unroll
        for (int e = 0; e < EPW; ++e) {
            // softmax over m in each 16-lane row (no max-sub: logits bounded;
            // inactive lanes contribute exp=0). All 4 kq rows identical.
            float c[7];
            #pragma unroll
            for (int n = 0; n < 7; ++n) {
                float ev = active ? __expf(blog[e][n]) : 0.f;
                float sm = row16_sum(ev);
                c[n] = ev * rcpf_(sm);
            }
            float s[4];
            #pragma unroll
            for (int kk = 0; kk < 4; ++kk) s[kk] = 0.f;
            #pragma unroll
            for (int n = 0; n < 7; ++n) {
                float cn = c[n];
                #pragma unroll
                for (int kk = 0; kk < 4; ++kk) s[kk] += cn * uh[e][n][kk];
            }
            float s2l = 0.f;
            #pragma unroll
            for (int kk = 0; kk < 4; ++kk) s2l += s[kk] * s[kk];
            float s2 = kq_sum(s2l);
            float nrm = sqrtf(s2);
            float f = nrm * rcpf_((1.f + s2) * (nrm + 1e-8f));
            if (it == niter - 1) {
                vnorm[e] = f * nrm;
            } else {
                #pragma unroll
                for (int kk = 0; kk < 4; ++kk) s[kk] *= f;   // s -> v
                #pragma unroll
                for (int n = 0; n < 7; ++n) {
                    float dl = 0.f;
                    #pragma unroll
                    for (int kk = 0; kk < 4; ++kk) dl += uh[e][n][kk] * s[kk];
                    blog[e][n] += kq_sum(dl);
                }
            }
        }
    }

    if (active && (kq == 0)) {
        #pragma unroll
        for (int e = 0; e < EPW; ++e)
            out[(size_t)(b0 + e) * 12 + t] = vnorm[e];
    }
}

extern "C" void kernel_launch(void* const* d_in, const int* in_sizes, int n_in,
                              void* d_out, int out_size, void* d_ws, size_t ws_size,
                              hipStream_t stream) {
    const float* x    = (const float*)d_in[0];
    const float* W_pc = (const float*)d_in[1];
    const float* b_pc = (const float*)d_in[2];
    const float* W    = (const float*)d_in[3];
    const int* niter  = (const int*)d_in[4];
    float* out = (float*)d_out;

    int B = in_sizes[0] / 210;
    int elems_per_block = WPB * EPW;
    int blocks = (B + elems_per_block - 1) / elems_per_block;

    capsnet_kernel<<<blocks, THREADS, 0, stream>>>(x, W_pc, b_pc, W, niter, out, B);
}